// Round 2
// baseline (1047.203 us; speedup 1.0000x reference)
//
#include <hip/hip_runtime.h>
#include <stdint.h>

#define B_N 32
#define C_N 512
#define HEADS_N 8
#define D_N 64
#define N_SP 4096   // H*W

typedef __attribute__((ext_vector_type(8))) short short8;
typedef __attribute__((ext_vector_type(4))) float f32x4;

__device__ __forceinline__ unsigned int f2bf1(float x) {
  unsigned int u = __float_as_uint(x);
  return (u + 0x7fffu + ((u >> 16) & 1u)) >> 16;   // RNE fp32 -> bf16
}
__device__ __forceinline__ unsigned int packbf(float lo, float hi) {
  return f2bf1(lo) | (f2bf1(hi) << 16);
}

// ---------------------------------------------------------------------------
// Kernel A1: split-K partial raw-score GEMM. Grid (HEADS, B, splitk).
// Each block: 64x64 raw q.k^T over a K-chunk of 4096/splitk spatial columns
// (bf16 MFMA) + fp32 partial sum-of-squares. Writes RAW partials to ws.
// LDS = tiles only (18.4 KB): ssq reduced via 16-lane shuffles -> ~6-8
// blocks/CU resident (was ~5). This phase moves 512 MB; must be BW-bound.
// ---------------------------------------------------------------------------
__global__ __launch_bounds__(256, 6) void attn_partial_kernel(
    const float* __restrict__ localf, const float* __restrict__ globf,
    float* __restrict__ pS, float* __restrict__ pssq, int splitk)
{
  const int h = blockIdx.x, b = blockIdx.y, chunk = blockIdx.z;
  const int t = threadIdx.x;
  const int lane = t & 63, w = t >> 6;
  const int rquad = t >> 4;   // 0..15
  const int c4 = t & 15;      // float4 column within 64-wide tile

  __shared__ unsigned short tA[64 * 72];  // [row][k] stride 72 shorts = 144 B
  __shared__ unsigned short tB[64 * 72];

  const float* Qb = localf + ((size_t)(b * C_N + h * D_N)) * N_SP;
  const float* Kb = globf  + ((size_t)(b * C_N + h * D_N)) * N_SP;

  const int iters = 64 / splitk;
  const int it0 = chunk * iters;

  f32x4 acc[2][2];
#pragma unroll
  for (int i = 0; i < 2; ++i)
#pragma unroll
    for (int j = 0; j < 2; ++j) acc[i][j] = (f32x4){0.f, 0.f, 0.f, 0.f};

  float ssqA[4] = {0.f, 0.f, 0.f, 0.f}, ssqB[4] = {0.f, 0.f, 0.f, 0.f};
  f32x4 qa[4], ka[4];

  // prefetch first tile of this chunk
  {
    int n0 = it0 * 64 + c4 * 4;
#pragma unroll
    for (int i = 0; i < 4; ++i) {
      int row = i * 16 + rquad;
      qa[i] = *(const f32x4*)(Qb + (size_t)row * N_SP + n0);
      ka[i] = *(const f32x4*)(Kb + (size_t)row * N_SP + n0);
    }
  }

  const int lr = lane & 15, lq = lane >> 4;
  const int rbase = (w >> 1) * 32, cbase = (w & 1) * 32;

  for (int it = it0; it < it0 + iters; ++it) {
    // write staged regs -> LDS (bf16), accumulate sum-of-squares in fp32
#pragma unroll
    for (int i = 0; i < 4; ++i) {
      int row = i * 16 + rquad;
      f32x4 q = qa[i], k = ka[i];
      ssqA[i] += q[0]*q[0] + q[1]*q[1] + q[2]*q[2] + q[3]*q[3];
      ssqB[i] += k[0]*k[0] + k[1]*k[1] + k[2]*k[2] + k[3]*k[3];
      uint2 qp; qp.x = packbf(q[0], q[1]); qp.y = packbf(q[2], q[3]);
      uint2 kp; kp.x = packbf(k[0], k[1]); kp.y = packbf(k[2], k[3]);
      *(uint2*)(tA + row * 72 + c4 * 4) = qp;
      *(uint2*)(tB + row * 72 + c4 * 4) = kp;
    }
    __syncthreads();
    // prefetch next tile while MFMAs run
    if (it + 1 < it0 + iters) {
      int n0 = (it + 1) * 64 + c4 * 4;
#pragma unroll
      for (int i = 0; i < 4; ++i) {
        int row = i * 16 + rquad;
        qa[i] = *(const f32x4*)(Qb + (size_t)row * N_SP + n0);
        ka[i] = *(const f32x4*)(Kb + (size_t)row * N_SP + n0);
      }
    }
#pragma unroll
    for (int s = 0; s < 2; ++s) {
      short8 af[2], bf[2];
#pragma unroll
      for (int mt = 0; mt < 2; ++mt)
        af[mt] = *(const short8*)(tA + (rbase + mt * 16 + lr) * 72 + (s * 4 + lq) * 8);
#pragma unroll
      for (int nt = 0; nt < 2; ++nt)
        bf[nt] = *(const short8*)(tB + (cbase + nt * 16 + lr) * 72 + (s * 4 + lq) * 8);
#pragma unroll
      for (int mt = 0; mt < 2; ++mt)
#pragma unroll
        for (int nt = 0; nt < 2; ++nt)
          acc[mt][nt] = __builtin_amdgcn_mfma_f32_16x16x32_bf16(
              af[mt], bf[nt], acc[mt][nt], 0, 0, 0);
    }
    __syncthreads();
  }

  const size_t obase = (size_t)(b * HEADS_N + h) * (size_t)splitk + chunk;

  // reduce ssq across the 16 lanes (c4) sharing each row; write raw partials
#pragma unroll
  for (int i = 0; i < 4; ++i) {
    float a = ssqA[i], bb = ssqB[i];
#pragma unroll
    for (int m = 8; m >= 1; m >>= 1) {
      a  += __shfl_xor(a, m, 64);
      bb += __shfl_xor(bb, m, 64);
    }
    if (c4 == 0) {
      int row = i * 16 + rquad;
      pssq[obase * 128 + row]      = a;
      pssq[obase * 128 + 64 + row] = bb;
    }
  }

  // raw partial scores out
  float* ps = pS + obase * 4096;
#pragma unroll
  for (int mt = 0; mt < 2; ++mt)
#pragma unroll
    for (int nt = 0; nt < 2; ++nt)
#pragma unroll
      for (int r = 0; r < 4; ++r) {
        int rg = rbase + mt * 16 + lq * 4 + r;   // C/D layout: row=(lane>>4)*4+reg
        int cg = cbase + nt * 16 + lr;           //             col=lane&15
        ps[rg * 64 + cg] = acc[mt][nt][r];
      }
}

// ---------------------------------------------------------------------------
// Kernel A2: combine partials -> L2-norm scale -> temperature -> row softmax.
// Grid (HEADS, B), 256 threads. Tiny: reads splitk*16KB + writes 16KB/block.
// ---------------------------------------------------------------------------
__global__ __launch_bounds__(256) void attn_combine_kernel(
    const float* __restrict__ pS, const float* __restrict__ pssq,
    const float* __restrict__ temp, float* __restrict__ attn_out, int splitk)
{
  const int h = blockIdx.x, b = blockIdx.y, t = threadIdx.x;
  __shared__ float S[64 * 68];
  __shared__ float invv[128];

  const size_t base = (size_t)(b * HEADS_N + h) * (size_t)splitk;

  float r[16];
#pragma unroll
  for (int i = 0; i < 16; ++i) r[i] = 0.f;
  for (int c = 0; c < splitk; ++c) {
    const float* p = pS + (base + c) * 4096;
#pragma unroll
    for (int i = 0; i < 16; ++i) r[i] += p[t + 256 * i];
  }
  if (t < 128) {
    float s = 0.f;
    for (int c = 0; c < splitk; ++c) s += pssq[(base + c) * 128 + t];
    invv[t] = 1.0f / fmaxf(sqrtf(s), 1e-12f);
  }
#pragma unroll
  for (int i = 0; i < 16; ++i) {
    int e = t + 256 * i;
    S[(e >> 6) * 68 + (e & 63)] = r[i];
  }
  __syncthreads();

  const float tval = temp[h];
#pragma unroll
  for (int i = 0; i < 16; ++i) {
    int e = t + 256 * i;
    int rw = e >> 6, cl = e & 63;
    S[rw * 68 + cl] *= invv[rw] * invv[64 + cl] * tval;
  }
  __syncthreads();

  // row softmax (64 rows, one thread each), write attn fp32 to workspace
  if (t < 64) {
    float mx = -1e30f;
#pragma unroll 8
    for (int j = 0; j < 64; ++j) mx = fmaxf(mx, S[t * 68 + j]);
    float sum = 0.f;
#pragma unroll 8
    for (int j = 0; j < 64; ++j) {
      float e = __expf(S[t * 68 + j] - mx);
      S[t * 68 + j] = e;
      sum += e;
    }
    float inv = 1.0f / sum;
    float* op = attn_out + ((size_t)((b * HEADS_N + h) * 64 + t)) * 64;
#pragma unroll 8
    for (int j = 0; j < 64; ++j) op[j] = S[t * 68 + j] * inv;
  }
}

// ---------------------------------------------------------------------------
// Kernel B: fold projection through attention:
//   M[b][o][h*64+e] = sum_cc P[o][h*64+cc] * attn[b,h,cc,e],  stored bf16.
// z-split 8 ways (2048 blocks) for latency hiding.
// ---------------------------------------------------------------------------
__global__ __launch_bounds__(256) void fold_kernel(
    const float* __restrict__ proj, const float* __restrict__ attn,
    unsigned short* __restrict__ Mout)
{
  const int h = blockIdx.x, b = blockIdx.y, zh = blockIdx.z;
  const int t = threadIdx.x;
  __shared__ float A_[64 * 64];
  const float* ap = attn + (size_t)(b * HEADS_N + h) * 4096;
#pragma unroll
  for (int i = 0; i < 16; ++i) A_[i * 256 + t] = ap[i * 256 + t];
  __syncthreads();
  const int e = t & 63, w = t >> 6;
  float col[64];
#pragma unroll
  for (int cc = 0; cc < 64; ++cc) col[cc] = A_[cc * 64 + e];
  unsigned short* mb = Mout + (size_t)b * C_N * C_N + (size_t)h * 64 + e;
  for (int i = 0; i < 16; ++i) {
    int o = zh * 64 + i * 4 + w;
    const float* pr = proj + (size_t)o * C_N + h * 64;
    float s = 0.f;
#pragma unroll
    for (int cc = 0; cc < 64; cc += 4) {
      f32x4 p = *(const f32x4*)(pr + cc);
      s += p[0]*col[cc] + p[1]*col[cc+1] + p[2]*col[cc+2] + p[3]*col[cc+3];
    }
    mb[(size_t)o * C_N] = (unsigned short)f2bf1(s);
  }
}

// ---------------------------------------------------------------------------
// Kernel C: final GEMM, per b: out[b] = M_b (512x512 bf16) @ G_b (512x4096).
// 128x128 tiles, BK=64, bf16 MFMA. B operand transposed+converted in LDS.
// Epilogue transposes acc through (reused) LDS so each wave stores 4x256 B
// fully-covered segments -> full 128 B lines, no partial-line write-amp.
// __launch_bounds__(256,4): 4 blocks/CU (LDS 4x36.8 KB = 147 KB <= 160 KB).
// ---------------------------------------------------------------------------
__global__ __launch_bounds__(256, 4) void final_gemm_kernel(
    const unsigned short* __restrict__ Mw, const float* __restrict__ globf,
    float* __restrict__ outp)
{
  const int nt0 = blockIdx.x;   // n tile (32)
  const int mt0 = blockIdx.y;   // o tile (4)
  const int b   = blockIdx.z;   // batch (32)
  const int t = threadIdx.x, lane = t & 63, w = t >> 6;
  const int lr = lane & 15, lq = lane >> 4;

  __shared__ unsigned short tA[128 * 72];  // [o][k]  pad-only
  __shared__ unsigned short tB[128 * 72];  // [n][k]  pad + xor swizzle

  const unsigned short* Mb = Mw + ((size_t)b * C_N + mt0 * 128) * C_N;
  const float* Gb = globf + (size_t)b * C_N * N_SP + nt0 * 128;

  f32x4 acc[4][4];
#pragma unroll
  for (int i = 0; i < 4; ++i)
#pragma unroll
    for (int j = 0; j < 4; ++j) acc[i][j] = (f32x4){0.f, 0.f, 0.f, 0.f};

  const int mq = (w >> 1) * 64, nq2 = (w & 1) * 64;
  const int nq = t & 31, kg = t >> 5;   // B-staging work split

  int4 av[4];
  f32x4 gv[8];

  // prefetch kb = 0
  {
#pragma unroll
    for (int i = 0; i < 4; ++i) {
      int u = t + 256 * i; int o = u >> 3, j = u & 7;
      av[i] = *(const int4*)(Mb + (size_t)o * C_N + j * 8);
    }
    const float* gp = Gb + (size_t)(kg * 8) * N_SP + nq * 4;
#pragma unroll
    for (int i = 0; i < 8; ++i) gv[i] = *(const f32x4*)(gp + (size_t)i * N_SP);
  }

  for (int kb = 0; kb < 8; ++kb) {
    // ---- stage regs -> LDS ----
#pragma unroll
    for (int i = 0; i < 4; ++i) {
      int u = t + 256 * i; int o = u >> 3, j = u & 7;
      *(int4*)(tA + o * 72 + j * 8) = av[i];
    }
#pragma unroll
    for (int r = 0; r < 4; ++r) {
      int n = nq * 4 + r;
      int4 pk;
      pk.x = (int)packbf(gv[0][r], gv[1][r]);
      pk.y = (int)packbf(gv[2][r], gv[3][r]);
      pk.z = (int)packbf(gv[4][r], gv[5][r]);
      pk.w = (int)packbf(gv[6][r], gv[7][r]);
      int gph = kg ^ (nq & 7);
      *(int4*)(tB + n * 72 + gph * 8) = pk;
    }
    __syncthreads();
    // ---- prefetch next K-slab while MFMAs run ----
    if (kb < 7) {
      int kn = (kb + 1) * 64;
#pragma unroll
      for (int i = 0; i < 4; ++i) {
        int u = t + 256 * i; int o = u >> 3, j = u & 7;
        av[i] = *(const int4*)(Mb + (size_t)o * C_N + kn + j * 8);
      }
      const float* gp = Gb + (size_t)(kn + kg * 8) * N_SP + nq * 4;
#pragma unroll
      for (int i = 0; i < 8; ++i) gv[i] = *(const f32x4*)(gp + (size_t)i * N_SP);
    }
    // ---- MFMA ----
#pragma unroll
    for (int s = 0; s < 2; ++s) {
      short8 af[4], bf[4];
#pragma unroll
      for (int mt = 0; mt < 4; ++mt)
        af[mt] = *(const short8*)(tA + (mq + mt * 16 + lr) * 72 + (s * 4 + lq) * 8);
#pragma unroll
      for (int nt = 0; nt < 4; ++nt) {
        int n = nq2 + nt * 16 + lr;
        int g2 = (s * 4 + lq) ^ ((n >> 2) & 7);
        bf[nt] = *(const short8*)(tB + n * 72 + g2 * 8);
      }
#pragma unroll
      for (int mt = 0; mt < 4; ++mt)
#pragma unroll
        for (int nt = 0; nt < 4; ++nt)
          acc[mt][nt] = __builtin_amdgcn_mfma_f32_16x16x32_bf16(
              af[mt], bf[nt], acc[mt][nt], 0, 0, 0);
    }
    __syncthreads();
  }

  // ---- epilogue: transpose acc via LDS (reuse tA), float4 stores ----
  // Each wave owns a private 16x68 float scratch; lane stores 16 B
  // contiguous, wave instr covers 4 rows x 256 B -> full-line writes.
  float* E = (float*)tA;               // 4 waves * 16*68 * 4B = 17408 B <= tA
  float* E_w = E + w * (16 * 68);
#pragma unroll
  for (int mt = 0; mt < 4; ++mt) {
    __syncthreads();
#pragma unroll
    for (int nt = 0; nt < 4; ++nt)
#pragma unroll
      for (int r = 0; r < 4; ++r)
        E_w[(lq * 4 + r) * 68 + nt * 16 + lr] = acc[mt][nt][r];
    __syncthreads();
    float* ob = outp + ((size_t)(b * C_N + mt0 * 128 + mq + mt * 16)) * N_SP
              + nt0 * 128 + nq2;
#pragma unroll
    for (int rr = 0; rr < 4; ++rr) {
      int row = rr * 4 + lq;
      f32x4 v = *(const f32x4*)(E_w + row * 68 + lr * 4);
      *(f32x4*)(ob + (size_t)row * N_SP + lr * 4) = v;
    }
  }
}

// ---------------------------------------------------------------------------
extern "C" void kernel_launch(void* const* d_in, const int* in_sizes, int n_in,
                              void* d_out, int out_size, void* d_ws, size_t ws_size,
                              hipStream_t stream) {
  const float* localf = (const float*)d_in[0];
  const float* globf  = (const float*)d_in[1];
  const float* temp   = (const float*)d_in[2];
  const float* proj   = (const float*)d_in[3];
  float* out = (float*)d_out;

  // workspace layout: attn fp32 (4 MB) | M bf16 (16 MB) | pS | pssq
  const size_t ATTN_BYTES = (size_t)B_N * HEADS_N * 64 * 64 * sizeof(float);
  const size_t M_BYTES    = (size_t)B_N * C_N * C_N * sizeof(unsigned short);

  int splitk = 8;
  while (splitk > 1) {
    size_t need = ATTN_BYTES + M_BYTES +
                  (size_t)B_N * HEADS_N * (size_t)splitk * (4096 + 128) * sizeof(float);
    if (need <= ws_size) break;
    splitk >>= 1;
  }

  float* attn_ws = (float*)d_ws;
  unsigned short* M_ws = (unsigned short*)((char*)d_ws + ATTN_BYTES);
  float* pS   = (float*)((char*)d_ws + ATTN_BYTES + M_BYTES);
  float* pssq = pS + (size_t)B_N * HEADS_N * (size_t)splitk * 4096;

  attn_partial_kernel<<<dim3(HEADS_N, B_N, splitk), 256, 0, stream>>>(
      localf, globf, pS, pssq, splitk);
  attn_combine_kernel<<<dim3(HEADS_N, B_N), 256, 0, stream>>>(
      pS, pssq, temp, attn_ws, splitk);
  fold_kernel<<<dim3(HEADS_N, B_N, 8), 256, 0, stream>>>(proj, attn_ws, M_ws);
  final_gemm_kernel<<<dim3(32, 4, B_N), 256, 0, stream>>>(M_ws, globf, out);
}

// Round 3
// 925.629 us; speedup vs baseline: 1.1313x; 1.1313x over previous
//
#include <hip/hip_runtime.h>
#include <stdint.h>

#define B_N 32
#define C_N 512
#define HEADS_N 8
#define D_N 64
#define N_SP 4096   // H*W

typedef __attribute__((ext_vector_type(8))) short short8;
typedef __attribute__((ext_vector_type(4))) float f32x4;

__device__ __forceinline__ unsigned int f2bf1(float x) {
  unsigned int u = __float_as_uint(x);
  return (u + 0x7fffu + ((u >> 16) & 1u)) >> 16;   // RNE fp32 -> bf16
}
__device__ __forceinline__ unsigned int packbf(float lo, float hi) {
  return f2bf1(lo) | (f2bf1(hi) << 16);
}

// ---------------------------------------------------------------------------
// Kernel A1: split-K partial raw-score GEMM. Grid (HEADS, B, splitk).
// 64x64 raw q.k^T over a K-chunk (bf16 MFMA) + fp32 partial sum-of-squares.
// Streaming loads/stores are nontemporal (zero reuse device-wide).
// NOTE: no min-waves bound -- (256,6) in the last round forced VGPR spills.
// ---------------------------------------------------------------------------
__global__ __launch_bounds__(256) void attn_partial_kernel(
    const float* __restrict__ localf, const float* __restrict__ globf,
    float* __restrict__ pS, float* __restrict__ pssq, int splitk)
{
  const int h = blockIdx.x, b = blockIdx.y, chunk = blockIdx.z;
  const int t = threadIdx.x;
  const int lane = t & 63, w = t >> 6;
  const int rquad = t >> 4;   // 0..15
  const int c4 = t & 15;      // float4 column within 64-wide tile

  __shared__ unsigned short tA[64 * 72];  // [row][k] stride 72 shorts = 144 B
  __shared__ unsigned short tB[64 * 72];

  const float* Qb = localf + ((size_t)(b * C_N + h * D_N)) * N_SP;
  const float* Kb = globf  + ((size_t)(b * C_N + h * D_N)) * N_SP;

  const int iters = 64 / splitk;
  const int it0 = chunk * iters;

  f32x4 acc[2][2];
#pragma unroll
  for (int i = 0; i < 2; ++i)
#pragma unroll
    for (int j = 0; j < 2; ++j) acc[i][j] = (f32x4){0.f, 0.f, 0.f, 0.f};

  float ssqA[4] = {0.f, 0.f, 0.f, 0.f}, ssqB[4] = {0.f, 0.f, 0.f, 0.f};
  f32x4 qa[4], ka[4];

  // prefetch first tile of this chunk (nontemporal: pure streaming)
  {
    int n0 = it0 * 64 + c4 * 4;
#pragma unroll
    for (int i = 0; i < 4; ++i) {
      int row = i * 16 + rquad;
      qa[i] = __builtin_nontemporal_load((const f32x4*)(Qb + (size_t)row * N_SP + n0));
      ka[i] = __builtin_nontemporal_load((const f32x4*)(Kb + (size_t)row * N_SP + n0));
    }
  }

  const int lr = lane & 15, lq = lane >> 4;
  const int rbase = (w >> 1) * 32, cbase = (w & 1) * 32;

  for (int it = it0; it < it0 + iters; ++it) {
    // write staged regs -> LDS (bf16), accumulate sum-of-squares in fp32
#pragma unroll
    for (int i = 0; i < 4; ++i) {
      int row = i * 16 + rquad;
      f32x4 q = qa[i], k = ka[i];
      ssqA[i] += q[0]*q[0] + q[1]*q[1] + q[2]*q[2] + q[3]*q[3];
      ssqB[i] += k[0]*k[0] + k[1]*k[1] + k[2]*k[2] + k[3]*k[3];
      uint2 qp; qp.x = packbf(q[0], q[1]); qp.y = packbf(q[2], q[3]);
      uint2 kp; kp.x = packbf(k[0], k[1]); kp.y = packbf(k[2], k[3]);
      *(uint2*)(tA + row * 72 + c4 * 4) = qp;
      *(uint2*)(tB + row * 72 + c4 * 4) = kp;
    }
    __syncthreads();
    // prefetch next tile while MFMAs run
    if (it + 1 < it0 + iters) {
      int n0 = (it + 1) * 64 + c4 * 4;
#pragma unroll
      for (int i = 0; i < 4; ++i) {
        int row = i * 16 + rquad;
        qa[i] = __builtin_nontemporal_load((const f32x4*)(Qb + (size_t)row * N_SP + n0));
        ka[i] = __builtin_nontemporal_load((const f32x4*)(Kb + (size_t)row * N_SP + n0));
      }
    }
#pragma unroll
    for (int s = 0; s < 2; ++s) {
      short8 af[2], bf[2];
#pragma unroll
      for (int mt = 0; mt < 2; ++mt)
        af[mt] = *(const short8*)(tA + (rbase + mt * 16 + lr) * 72 + (s * 4 + lq) * 8);
#pragma unroll
      for (int nt = 0; nt < 2; ++nt)
        bf[nt] = *(const short8*)(tB + (cbase + nt * 16 + lr) * 72 + (s * 4 + lq) * 8);
#pragma unroll
      for (int mt = 0; mt < 2; ++mt)
#pragma unroll
        for (int nt = 0; nt < 2; ++nt)
          acc[mt][nt] = __builtin_amdgcn_mfma_f32_16x16x32_bf16(
              af[mt], bf[nt], acc[mt][nt], 0, 0, 0);
    }
    __syncthreads();
  }

  const size_t obase = (size_t)(b * HEADS_N + h) * (size_t)splitk + chunk;

  // reduce ssq across the 16 lanes (c4) sharing each row; write raw partials
#pragma unroll
  for (int i = 0; i < 4; ++i) {
    float a = ssqA[i], bb = ssqB[i];
#pragma unroll
    for (int m = 8; m >= 1; m >>= 1) {
      a  += __shfl_xor(a, m, 64);
      bb += __shfl_xor(bb, m, 64);
    }
    if (c4 == 0) {
      int row = i * 16 + rquad;
      pssq[obase * 128 + row]      = a;
      pssq[obase * 128 + 64 + row] = bb;
    }
  }

  // raw partial scores out (nontemporal: consumed by a later kernel)
  float* ps = pS + obase * 4096;
#pragma unroll
  for (int mt = 0; mt < 2; ++mt)
#pragma unroll
    for (int nt = 0; nt < 2; ++nt)
#pragma unroll
      for (int r = 0; r < 4; ++r) {
        int rg = rbase + mt * 16 + lq * 4 + r;   // C/D layout: row=(lane>>4)*4+reg
        int cg = cbase + nt * 16 + lr;           //             col=lane&15
        __builtin_nontemporal_store(acc[mt][nt][r], ps + rg * 64 + cg);
      }
}

// ---------------------------------------------------------------------------
// Kernel A2+B merged: combine partials -> L2-norm scale -> softmax -> fold
// projection through attention:
//   M[b][o][h*64+e] = sum_cc proj[o][h*64+cc] * attn[b,h,cc,e]   (bf16 out)
// Grid (HEADS, B), 256 threads. LDS: ST = attn^T at odd stride 69
// (conflict-free scalar reads), SP overlaid: scores (phase 1) / proj chunk
// (phase 2). proj reads are wave-uniform -> LDS broadcast.
// ---------------------------------------------------------------------------
__global__ __launch_bounds__(256) void combine_fold_kernel(
    const float* __restrict__ pS, const float* __restrict__ pssq,
    const float* __restrict__ temp, const float* __restrict__ proj,
    unsigned short* __restrict__ Mout, int splitk)
{
  const int h = blockIdx.x, b = blockIdx.y, t = threadIdx.x;
  __shared__ float ST[64 * 69];    // attn transposed [e][cc], odd stride
  __shared__ float SP[128 * 68];   // phase1: scores S[64][68]; phase2: proj chunk
  __shared__ float invv[128];
  float* S = SP;

  const size_t base = (size_t)(b * HEADS_N + h) * (size_t)splitk;

  // ---- phase 1: combine raw partials ----
  float r[16];
#pragma unroll
  for (int i = 0; i < 16; ++i) r[i] = 0.f;
  for (int c = 0; c < splitk; ++c) {
    const float* p = pS + (base + c) * 4096;
#pragma unroll
    for (int i = 0; i < 16; ++i) r[i] += p[t + 256 * i];
  }
  if (t < 128) {
    float s = 0.f;
    for (int c = 0; c < splitk; ++c) s += pssq[(base + c) * 128 + t];
    invv[t] = 1.0f / fmaxf(sqrtf(s), 1e-12f);
  }
#pragma unroll
  for (int i = 0; i < 16; ++i) {
    int e = t + 256 * i;
    S[(e >> 6) * 68 + (e & 63)] = r[i];
  }
  __syncthreads();

  // scale own elements (same-thread mapping as the writes above)
  const float tval = temp[h];
#pragma unroll
  for (int i = 0; i < 16; ++i) {
    int e = t + 256 * i;
    int rw = e >> 6, cl = e & 63;
    S[rw * 68 + cl] *= invv[rw] * invv[64 + cl] * tval;
  }
  __syncthreads();

  // row softmax (row = t < 64); write normalized attn TRANSPOSED into ST
  if (t < 64) {
    float mx = -1e30f;
#pragma unroll 8
    for (int j = 0; j < 64; ++j) mx = fmaxf(mx, S[t * 68 + j]);
    float sum = 0.f;
    float ex[64];
#pragma unroll 8
    for (int j = 0; j < 64; ++j) {
      float e = __expf(S[t * 68 + j] - mx);
      ex[j] = e;
      sum += e;
    }
    float inv = 1.0f / sum;
#pragma unroll 8
    for (int j = 0; j < 64; ++j) ST[j * 69 + t] = ex[j] * inv;
  }
  __syncthreads();   // ST ready; S (=SP) now dead

  // ---- phase 2: fold proj through attn, 4 chunks of 128 o-rows ----
  const int e = t & 63, w = t >> 6;
  unsigned short* mb = Mout + (size_t)b * C_N * C_N + (size_t)h * 64 + e;
  const float* STrow = ST + (size_t)e * 69;

  for (int chunk = 0; chunk < 4; ++chunk) {
    // stage proj rows [chunk*128, +128), cols [h*64, +64) -> SP[128][68]
#pragma unroll
    for (int i = 0; i < 32; ++i) {
      int row = i * 4 + w;
      SP[row * 68 + e] = proj[(size_t)(chunk * 128 + row) * C_N + h * 64 + e];
    }
    __syncthreads();
#pragma unroll 4
    for (int oi = 0; oi < 32; ++oi) {
      int ol = oi * 4 + w;                 // wave-uniform row
      const float* Pr = SP + ol * 68;
      float s = 0.f;
#pragma unroll
      for (int cc = 0; cc < 64; cc += 4) {
        s += Pr[cc]     * STrow[cc]     + Pr[cc + 1] * STrow[cc + 1]
           + Pr[cc + 2] * STrow[cc + 2] + Pr[cc + 3] * STrow[cc + 3];
      }
      int o = chunk * 128 + ol;
      mb[(size_t)o * C_N] = (unsigned short)f2bf1(s);
    }
    __syncthreads();
  }
}

// ---------------------------------------------------------------------------
// Kernel C: final GEMM, per b: out[b] = M_b (512x512 bf16) @ G_b (512x4096).
// 128x128 tiles, BK=64, bf16 MFMA. Round-1 structure ((256,2), reg-staged,
// xor-swizzled B tile). Single change: OUTPUT STORES ARE NONTEMPORAL --
// out lines stream to memory as fully-formed lines instead of sitting dirty
// in a thrashed L2 (theory for the measured 2.6x write amplification).
// ---------------------------------------------------------------------------
__global__ __launch_bounds__(256, 2) void final_gemm_kernel(
    const unsigned short* __restrict__ Mw, const float* __restrict__ globf,
    float* __restrict__ outp)
{
  const int nt0 = blockIdx.x;   // n tile (32)
  const int mt0 = blockIdx.y;   // o tile (4)
  const int b   = blockIdx.z;   // batch (32)
  const int t = threadIdx.x, lane = t & 63, w = t >> 6;
  const int lr = lane & 15, lq = lane >> 4;

  __shared__ unsigned short tA[128 * 72];  // [o][k]  pad-only
  __shared__ unsigned short tB[128 * 72];  // [n][k]  pad + xor swizzle

  const unsigned short* Mb = Mw + ((size_t)b * C_N + mt0 * 128) * C_N;
  const float* Gb = globf + (size_t)b * C_N * N_SP + nt0 * 128;

  f32x4 acc[4][4];
#pragma unroll
  for (int i = 0; i < 4; ++i)
#pragma unroll
    for (int j = 0; j < 4; ++j) acc[i][j] = (f32x4){0.f, 0.f, 0.f, 0.f};

  const int mq = (w >> 1) * 64, nq2 = (w & 1) * 64;
  const int nq = t & 31, kg = t >> 5;   // B-staging work split

  int4 av[4];
  f32x4 gv[8];

  // prefetch kb = 0
  {
#pragma unroll
    for (int i = 0; i < 4; ++i) {
      int u = t + 256 * i; int o = u >> 3, j = u & 7;
      av[i] = *(const int4*)(Mb + (size_t)o * C_N + j * 8);
    }
    const float* gp = Gb + (size_t)(kg * 8) * N_SP + nq * 4;
#pragma unroll
    for (int i = 0; i < 8; ++i) gv[i] = *(const f32x4*)(gp + (size_t)i * N_SP);
  }

  for (int kb = 0; kb < 8; ++kb) {
    // ---- stage regs -> LDS ----
#pragma unroll
    for (int i = 0; i < 4; ++i) {
      int u = t + 256 * i; int o = u >> 3, j = u & 7;
      *(int4*)(tA + o * 72 + j * 8) = av[i];
    }
#pragma unroll
    for (int r = 0; r < 4; ++r) {
      int n = nq * 4 + r;
      int4 pk;
      pk.x = (int)packbf(gv[0][r], gv[1][r]);
      pk.y = (int)packbf(gv[2][r], gv[3][r]);
      pk.z = (int)packbf(gv[4][r], gv[5][r]);
      pk.w = (int)packbf(gv[6][r], gv[7][r]);
      int gph = kg ^ (nq & 7);
      *(int4*)(tB + n * 72 + gph * 8) = pk;
    }
    __syncthreads();
    // ---- prefetch next K-slab while MFMAs run ----
    if (kb < 7) {
      int kn = (kb + 1) * 64;
#pragma unroll
      for (int i = 0; i < 4; ++i) {
        int u = t + 256 * i; int o = u >> 3, j = u & 7;
        av[i] = *(const int4*)(Mb + (size_t)o * C_N + kn + j * 8);
      }
      const float* gp = Gb + (size_t)(kn + kg * 8) * N_SP + nq * 4;
#pragma unroll
      for (int i = 0; i < 8; ++i) gv[i] = *(const f32x4*)(gp + (size_t)i * N_SP);
    }
    // ---- MFMA ----
#pragma unroll
    for (int s = 0; s < 2; ++s) {
      short8 af[4], bf[4];
#pragma unroll
      for (int mt = 0; mt < 4; ++mt)
        af[mt] = *(const short8*)(tA + (mq + mt * 16 + lr) * 72 + (s * 4 + lq) * 8);
#pragma unroll
      for (int nt = 0; nt < 4; ++nt) {
        int n = nq2 + nt * 16 + lr;
        int g2 = (s * 4 + lq) ^ ((n >> 2) & 7);
        bf[nt] = *(const short8*)(tB + n * 72 + g2 * 8);
      }
#pragma unroll
      for (int mt = 0; mt < 4; ++mt)
#pragma unroll
        for (int nt = 0; nt < 4; ++nt)
          acc[mt][nt] = __builtin_amdgcn_mfma_f32_16x16x32_bf16(
              af[mt], bf[nt], acc[mt][nt], 0, 0, 0);
    }
    __syncthreads();
  }

  // epilogue: nontemporal fp32 stores (64 B full segments per quarter-wave)
  float* ob = outp + ((size_t)(b * C_N + mt0 * 128 + mq)) * N_SP + nt0 * 128 + nq2;
#pragma unroll
  for (int mt = 0; mt < 4; ++mt)
#pragma unroll
    for (int nt = 0; nt < 4; ++nt)
#pragma unroll
      for (int r = 0; r < 4; ++r)
        __builtin_nontemporal_store(
            acc[mt][nt][r],
            ob + (size_t)(mt * 16 + lq * 4 + r) * N_SP + nt * 16 + lr);
}

// ---------------------------------------------------------------------------
extern "C" void kernel_launch(void* const* d_in, const int* in_sizes, int n_in,
                              void* d_out, int out_size, void* d_ws, size_t ws_size,
                              hipStream_t stream) {
  const float* localf = (const float*)d_in[0];
  const float* globf  = (const float*)d_in[1];
  const float* temp   = (const float*)d_in[2];
  const float* proj   = (const float*)d_in[3];
  float* out = (float*)d_out;

  // workspace layout: M bf16 (16 MB) | pS | pssq
  const size_t M_BYTES = (size_t)B_N * C_N * C_N * sizeof(unsigned short);

  int splitk = 8;
  while (splitk > 1) {
    size_t need = M_BYTES +
                  (size_t)B_N * HEADS_N * (size_t)splitk * (4096 + 128) * sizeof(float);
    if (need <= ws_size) break;
    splitk >>= 1;
  }

  unsigned short* M_ws = (unsigned short*)d_ws;
  float* pS   = (float*)((char*)d_ws + M_BYTES);
  float* pssq = pS + (size_t)B_N * HEADS_N * (size_t)splitk * 4096;

  attn_partial_kernel<<<dim3(HEADS_N, B_N, splitk), 256, 0, stream>>>(
      localf, globf, pS, pssq, splitk);
  combine_fold_kernel<<<dim3(HEADS_N, B_N), 256, 0, stream>>>(
      pS, pssq, temp, proj, M_ws, splitk);
  final_gemm_kernel<<<dim3(32, 4, B_N), 256, 0, stream>>>(M_ws, globf, out);
}